// Round 11
// baseline (266.309 us; speedup 1.0000x reference)
//
#include <hip/hip_runtime.h>
#include <math.h>

typedef int v4i  __attribute__((ext_vector_type(4)));
typedef int v16i __attribute__((ext_vector_type(16)));

#define DIM 4096
#define BM 256              // output tile (BM x BM)
#define BK 128              // K-tile bytes (int8) -- doubled to amortize sync
#define ATILE (BM * BK)     // 32768 B per operand tile
#define BUFSZ (2 * ATILE)   // 65536 B per buffer (A | B)

// ---------------------------------------------------------------------------
// async global->LDS 16B copy (wave-uniform base + lane*16 destination rule)
// ---------------------------------------------------------------------------
__device__ __forceinline__ void async16(const void* g, void* l) {
    __builtin_amdgcn_global_load_lds((__attribute__((address_space(1))) void*)(g),
                                     (__attribute__((address_space(3))) void*)(l),
                                     16, 0, 0);
}

// raw barrier / counted waitcnt (T4): no implicit vmcnt(0) drain.
#define VMCNT(N) asm volatile("s_waitcnt vmcnt(" #N ")" ::: "memory")
#define BARRIER() asm volatile("s_barrier" ::: "memory")

// ---------------------------------------------------------------------------
// Fused prep: blocks [0,4096) FWHT(256)+int4 quant; blocks [4096,20480)
// narrow int32 weights to int8.  Change vs verified version: the 16
// full-precision divisions per thread are replaced by 2 divisions + 16
// multiplies (rinv = 7/m; the 2^-4 FWHT normalization cancels exactly, so
// f_unscaled * (7/m_unscaled) == f_scaled * (7/m_scaled) bit-for-bit up to
// the one shared rounding of rinv).  Stored scale keeps the identical
// (m*0.0625)/7 expression -> same value as before.
// ---------------------------------------------------------------------------
__global__ __launch_bounds__(256) void prep(const float* __restrict__ x,
                                            const int* __restrict__ w,
                                            signed char* __restrict__ q,
                                            signed char* __restrict__ w8,
                                            float* __restrict__ scales) {
    if (blockIdx.x >= 4096) {
        int i = (blockIdx.x - 4096) * 256 + threadIdx.x;
        int4 v = ((const int4*)w)[i];
        char4 c;
        c.x = (signed char)v.x; c.y = (signed char)v.y;
        c.z = (signed char)v.z; c.w = (signed char)v.w;
        ((char4*)w8)[i] = c;
        return;
    }
    const int row  = blockIdx.x;
    const int lane = threadIdx.x & 63;
    const int wave = threadIdx.x >> 6;
    const float4* xr4 = (const float4*)(x + (size_t)row * DIM);

    float sgn[6];
    #pragma unroll
    for (int i = 0; i < 6; ++i) sgn[i] = (lane & (1 << i)) ? -1.0f : 1.0f;

    float f[4][4];                      // UNSCALED FWHT values (x 16 vs ref)
    #pragma unroll
    for (int b = 0; b < 4; ++b) {
        const int blk = wave + 4 * b;
        float4 v = xr4[blk * 64 + lane];
        float t0 = v.x + v.y, t1 = v.x - v.y;
        float t2 = v.z + v.w, t3 = v.z - v.w;
        f[b][0] = t0 + t2; f[b][1] = t1 + t3;
        f[b][2] = t0 - t2; f[b][3] = t1 - t3;
        #pragma unroll
        for (int st = 0; st < 6; ++st) {
            const int m = 1 << st;
            #pragma unroll
            for (int j = 0; j < 4; ++j) {
                float p = __shfl_xor(f[b][j], m, 64);
                f[b][j] = fmaf(sgn[st], f[b][j], p);
            }
        }
    }

    float m = 0.0f;
    #pragma unroll
    for (int b = 0; b < 4; ++b)
        #pragma unroll
        for (int j = 0; j < 4; ++j) m = fmaxf(m, fabsf(f[b][j]));
    #pragma unroll
    for (int d = 32; d; d >>= 1) m = fmaxf(m, __shfl_xor(m, d, 64));
    __shared__ float sm[4];
    if (lane == 0) sm[wave] = m;
    __syncthreads();
    m = fmaxf(fmaxf(sm[0], sm[1]), fmaxf(sm[2], sm[3]));

    // stored scale: identical expression to verified version (exact *2^-4,
    // then one rounding in /7)
    const float s = (m * 0.0625f) / 7.0f;
    if (threadIdx.x == 0) scales[row] = s;
    const float rinv = 7.0f / m;        // quant reciprocal (unscaled domain)

    char4* qr4 = (char4*)(q + (size_t)row * DIM);
    #pragma unroll
    for (int b = 0; b < 4; ++b) {
        const int blk = wave + 4 * b;
        char4 c;
        int qi;
        qi = (int)rintf(f[b][0] * rinv); c.x = (signed char)min(7, max(-8, qi));
        qi = (int)rintf(f[b][1] * rinv); c.y = (signed char)min(7, max(-8, qi));
        qi = (int)rintf(f[b][2] * rinv); c.z = (signed char)min(7, max(-8, qi));
        qi = (int)rintf(f[b][3] * rinv); c.w = (signed char)min(7, max(-8, qi));
        qr4[blk * 64 + lane] = c;
    }
}

// ---------------------------------------------------------------------------
// int8 GEMM, 256x256 tile, BK=128, 8 waves (2M x 4N), double-buffered LDS.
//
// R10 counters: sync overhead (~1400-1500 clk/K-tile: vmcnt+2 barriers+
// 8-wave straggle) dominates over MFMA (1170 clk).  BK=128 halves the
// substep count (32 vs 64) at constant per-substep sync cost -> overhead
// per MFMA halves.  1-deep prefetch suffices: vmcnt(8) now waits on loads
// issued a full ~3900-clk substep earlier.  Bank-swizzle: chunk ^= (row&7)
// over the 8 16B-chunks of each 128B row (measured-invariant 4 cyc/read
// penalty applies to every scheme tried; not the lever).
// S layout: [A0|B0][A1|B1], 64 KB each (128 KB total, 1 block/CU, 8 waves).
// ---------------------------------------------------------------------------
__global__ __launch_bounds__(512, 2) void gemm_q8(const signed char* __restrict__ A,
                                                  const signed char* __restrict__ B,
                                                  const float* __restrict__ rowScale,
                                                  const float* __restrict__ wscale,
                                                  const float* __restrict__ bias,
                                                  float* __restrict__ out) {
    __shared__ __align__(16) signed char S[2 * BUFSZ];   // 128 KB

    // XCD swizzle: 256 blocks -> each XCD a 4(bm) x 8(bn) rectangle.
    const int flat = blockIdx.y * gridDim.x + blockIdx.x;
    const int xcd  = flat & 7;
    const int idx  = flat >> 3;                 // 0..31
    const int bm   = ((xcd >> 1) << 2) + (idx & 3);
    const int bn   = ((xcd & 1) << 3) + (idx >> 2);

    const int t = threadIdx.x;
    const int lane = t & 63;
    const int wave = t >> 6;                    // 0..7
    const int wm = (wave >> 2) * 128;           // 2 waves in M
    const int wn = (wave & 3) * 64;             // 4 waves in N
    const int l31 = lane & 31, lh = lane >> 5;

    // --- staging: thread t covers chunks cidx = t + 512h, h=0..3, per tile
    const signed char* ga[4];
    const signed char* gb[4];
    int ldsA[4], ldsB[4];
    #pragma unroll
    for (int h = 0; h < 4; ++h) {
        const int cidx = t + 512 * h;           // 0..2047
        const int row  = cidx >> 3;             // 0..255
        const int g    = (cidx & 7) ^ (row & 7);// pre-swizzled global chunk
        ga[h] = A + (size_t)(bm * BM + row) * DIM + g * 16;
        gb[h] = B + (size_t)(bn * BM + row) * DIM + g * 16;
        ldsA[h] = cidx * 16;                    // linear LDS dest (A region)
        ldsB[h] = ATILE + cidx * 16;            // linear LDS dest (B region)
    }

    // --- loop-invariant read offsets (within one buffer); chunk = (2s+lh)^(r&7)
    int offA[4][4], offB[2][4];
    #pragma unroll
    for (int i = 0; i < 4; ++i)
        #pragma unroll
        for (int s = 0; s < 4; ++s) {
            const int r = wm + i * 32 + l31;
            offA[i][s] = r * BK + (((2 * s + lh) ^ (r & 7)) * 16);
        }
    #pragma unroll
    for (int j = 0; j < 2; ++j)
        #pragma unroll
        for (int s = 0; s < 4; ++s) {
            const int c = wn + j * 32 + l31;
            offB[j][s] = ATILE + c * BK + (((2 * s + lh) ^ (c & 7)) * 16);
        }

    v16i acc[4][2] = {};

#define STAGE(P) do {                                                          \
        _Pragma("unroll")                                                      \
        for (int h = 0; h < 4; ++h) {                                          \
            async16(ga[h], &S[(P) * BUFSZ + ldsA[h]]); ga[h] += BK;            \
            async16(gb[h], &S[(P) * BUFSZ + ldsB[h]]); gb[h] += BK;            \
        }                                                                      \
    } while (0)

#define COMPUTE(P) do {                                                        \
        __builtin_amdgcn_s_setprio(1);                                         \
        _Pragma("unroll")                                                      \
        for (int s = 0; s < 4; ++s) {                                          \
            const v4i a0 = *(const v4i*)&S[(P) * BUFSZ + offA[0][s]];          \
            const v4i a1 = *(const v4i*)&S[(P) * BUFSZ + offA[1][s]];          \
            const v4i a2 = *(const v4i*)&S[(P) * BUFSZ + offA[2][s]];          \
            const v4i a3 = *(const v4i*)&S[(P) * BUFSZ + offA[3][s]];          \
            const v4i b0 = *(const v4i*)&S[(P) * BUFSZ + offB[0][s]];          \
            const v4i b1 = *(const v4i*)&S[(P) * BUFSZ + offB[1][s]];          \
            acc[0][0] = __builtin_amdgcn_mfma_i32_32x32x32_i8(a0, b0, acc[0][0], 0, 0, 0); \
            acc[0][1] = __builtin_amdgcn_mfma_i32_32x32x32_i8(a0, b1, acc[0][1], 0, 0, 0); \
            acc[1][0] = __builtin_amdgcn_mfma_i32_32x32x32_i8(a1, b0, acc[1][0], 0, 0, 0); \
            acc[1][1] = __builtin_amdgcn_mfma_i32_32x32x32_i8(a1, b1, acc[1][1], 0, 0, 0); \
            acc[2][0] = __builtin_amdgcn_mfma_i32_32x32x32_i8(a2, b0, acc[2][0], 0, 0, 0); \
            acc[2][1] = __builtin_amdgcn_mfma_i32_32x32x32_i8(a2, b1, acc[2][1], 0, 0, 0); \
            acc[3][0] = __builtin_amdgcn_mfma_i32_32x32x32_i8(a3, b0, acc[3][0], 0, 0, 0); \
            acc[3][1] = __builtin_amdgcn_mfma_i32_32x32x32_i8(a3, b1, acc[3][1], 0, 0, 0); \
        }                                                                      \
        __builtin_amdgcn_s_setprio(0);                                         \
    } while (0)

    // 32 K-tiles, tile t -> buf t&1.  Steady state:
    //   STAGE(t+1); vmcnt(8) [t landed, t+1 in flight]; bar; COMPUTE(t); bar;
    // trailing bar guards buf t&1 against t+2's STAGE overwrite.
    STAGE(0);                                    // tile 0 -> buf0
    #pragma unroll 1
    for (int it = 0; it < 15; ++it) {
        STAGE(1); VMCNT(8); BARRIER(); COMPUTE(0); BARRIER();  // tile 2it
        STAGE(0); VMCNT(8); BARRIER(); COMPUTE(1); BARRIER();  // tile 2it+1
    }
    STAGE(1); VMCNT(8); BARRIER(); COMPUTE(0); BARRIER();      // tile 30
    VMCNT(0); BARRIER(); COMPUTE(1);                           // tile 31

#undef STAGE
#undef COMPUTE

    // epilogue: out[n,o] = acc * sx[n] * ws[o] + bias[o]
    // C/D: col = lane&31, row = (reg&3) + 8*(reg>>2) + 4*(lane>>5)  [m74/m101]
    #pragma unroll
    for (int j = 0; j < 2; ++j) {
        const int col = bn * BM + wn + j * 32 + l31;
        const float ws = wscale[col];
        const float bs = bias[col];
        #pragma unroll
        for (int i = 0; i < 4; ++i) {
            const int rb = bm * BM + wm + i * 32 + 4 * lh;
            #pragma unroll
            for (int r = 0; r < 16; ++r) {
                const int row = rb + (r & 3) + 8 * (r >> 2);
                out[(size_t)row * DIM + col] =
                    ((float)acc[i][j][r] * rowScale[row]) * ws + bs;
            }
        }
    }
}

// ---------------------------------------------------------------------------
extern "C" void kernel_launch(void* const* d_in, const int* in_sizes, int n_in,
                              void* d_out, int out_size, void* d_ws, size_t ws_size,
                              hipStream_t stream) {
    const float* x      = (const float*)d_in[0];
    const int*   wint   = (const int*)d_in[1];
    const float* wscale = (const float*)d_in[2];
    const float* bias   = (const float*)d_in[3];
    float* out = (float*)d_out;

    signed char* q8 = (signed char*)d_ws;                         // 16 MB
    signed char* w8 = q8 + (size_t)DIM * DIM;                     // 16 MB
    float* sx = (float*)(w8 + (size_t)DIM * DIM);                 // 16 KB

    prep<<<4096 + 16384, 256, 0, stream>>>(x, wint, q8, w8, sx);
    gemm_q8<<<dim3(DIM / BM, DIM / BM), 512, 0, stream>>>(q8, w8, sx, wscale, bias, out);
}

// Round 13
// 241.342 us; speedup vs baseline: 1.1034x; 1.1034x over previous
//
#include <hip/hip_runtime.h>
#include <math.h>

typedef int v4i  __attribute__((ext_vector_type(4)));
typedef int v16i __attribute__((ext_vector_type(16)));

#define DIM 4096
#define BM 256              // output tile (BM x BM)
#define BK 64               // K-tile bytes (int8)
#define ATILE (BM * BK)     // 16384 B per operand tile
#define BUFSZ (2 * ATILE)   // 32768 B per buffer (A | B)

// ---------------------------------------------------------------------------
// async global->LDS 16B copy (wave-uniform base + lane*16 destination rule)
// ---------------------------------------------------------------------------
__device__ __forceinline__ void async16(const void* g, void* l) {
    __builtin_amdgcn_global_load_lds((__attribute__((address_space(1))) void*)(g),
                                     (__attribute__((address_space(3))) void*)(l),
                                     16, 0, 0);
}

// raw barrier / counted waitcnt (T4): no implicit vmcnt(0) drain.
#define VMCNT(N) asm volatile("s_waitcnt vmcnt(" #N ")" ::: "memory")
#define BARRIER() asm volatile("s_barrier" ::: "memory")

// Bank swizzle over the 4 16B chunks of a 64B row (same as the passing R10).
__device__ __forceinline__ int swzC(int r) {
    return ((r >> 1) & 3) ^ ((r >> 3) & 3);
}

// ---------------------------------------------------------------------------
// Fused prep (R11 version, passed with identical absmax): FWHT(256)+quant
// via rinv multiply; weight narrowing int32->int8.
// ---------------------------------------------------------------------------
__global__ __launch_bounds__(256) void prep(const float* __restrict__ x,
                                            const int* __restrict__ w,
                                            signed char* __restrict__ q,
                                            signed char* __restrict__ w8,
                                            float* __restrict__ scales) {
    if (blockIdx.x >= 4096) {
        int i = (blockIdx.x - 4096) * 256 + threadIdx.x;
        int4 v = ((const int4*)w)[i];
        char4 c;
        c.x = (signed char)v.x; c.y = (signed char)v.y;
        c.z = (signed char)v.z; c.w = (signed char)v.w;
        ((char4*)w8)[i] = c;
        return;
    }
    const int row  = blockIdx.x;
    const int lane = threadIdx.x & 63;
    const int wave = threadIdx.x >> 6;
    const float4* xr4 = (const float4*)(x + (size_t)row * DIM);

    float sgn[6];
    #pragma unroll
    for (int i = 0; i < 6; ++i) sgn[i] = (lane & (1 << i)) ? -1.0f : 1.0f;

    float f[4][4];                      // UNSCALED FWHT values (x 16 vs ref)
    #pragma unroll
    for (int b = 0; b < 4; ++b) {
        const int blk = wave + 4 * b;
        float4 v = xr4[blk * 64 + lane];
        float t0 = v.x + v.y, t1 = v.x - v.y;
        float t2 = v.z + v.w, t3 = v.z - v.w;
        f[b][0] = t0 + t2; f[b][1] = t1 + t3;
        f[b][2] = t0 - t2; f[b][3] = t1 - t3;
        #pragma unroll
        for (int st = 0; st < 6; ++st) {
            const int m = 1 << st;
            #pragma unroll
            for (int j = 0; j < 4; ++j) {
                float p = __shfl_xor(f[b][j], m, 64);
                f[b][j] = fmaf(sgn[st], f[b][j], p);
            }
        }
    }

    float m = 0.0f;
    #pragma unroll
    for (int b = 0; b < 4; ++b)
        #pragma unroll
        for (int j = 0; j < 4; ++j) m = fmaxf(m, fabsf(f[b][j]));
    #pragma unroll
    for (int d = 32; d; d >>= 1) m = fmaxf(m, __shfl_xor(m, d, 64));
    __shared__ float sm[4];
    if (lane == 0) sm[wave] = m;
    __syncthreads();
    m = fmaxf(fmaxf(sm[0], sm[1]), fmaxf(sm[2], sm[3]));

    const float s = (m * 0.0625f) / 7.0f;   // identical value to verified ver.
    if (threadIdx.x == 0) scales[row] = s;
    const float rinv = 7.0f / m;            // quant reciprocal (unscaled dom.)

    char4* qr4 = (char4*)(q + (size_t)row * DIM);
    #pragma unroll
    for (int b = 0; b < 4; ++b) {
        const int blk = wave + 4 * b;
        char4 c;
        int qi;
        qi = (int)rintf(f[b][0] * rinv); c.x = (signed char)min(7, max(-8, qi));
        qi = (int)rintf(f[b][1] * rinv); c.y = (signed char)min(7, max(-8, qi));
        qi = (int)rintf(f[b][2] * rinv); c.z = (signed char)min(7, max(-8, qi));
        qi = (int)rintf(f[b][3] * rinv); c.w = (signed char)min(7, max(-8, qi));
        qr4[blk * 64 + lane] = c;
    }
}

// ---------------------------------------------------------------------------
// int8 GEMM, 256x256 tile, BK=64, 8 waves (2M x 4N), quad-buffered LDS.
// Staging skeleton = R10 (best measured: 86.7 us): 3-deep prefetch,
// VMCNT(8) counted, one stage per K-tile.  NEW: intra-tile 2-phase split
// (m201 pattern): barriers carve each substep into {VMEM+ds_read} and
// {MFMA cluster} regions so the 2 waves/SIMD alternate roles (one feeds
// the LDS port while the other feeds the matrix pipe) instead of the
// all-read-then-all-MFMA convoy (R10: MfmaUtil 33%).  setprio biases the
// arbitration toward MFMA-entering waves (T5: pays only on phase-split).
// Hazards identical to R10: VMCNT(8)+bar before first read of tile t;
// STAGE(t+3) overwrites buf[(t-1)&3] only after bar #1, by which point
// every wave's tile-(t-1) reads were consumed by its s1-MFMA cluster.
// ---------------------------------------------------------------------------
__global__ __launch_bounds__(512, 2) void gemm_q8(const signed char* __restrict__ A,
                                                  const signed char* __restrict__ B,
                                                  const float* __restrict__ rowScale,
                                                  const float* __restrict__ wscale,
                                                  const float* __restrict__ bias,
                                                  float* __restrict__ out) {
    __shared__ __align__(16) signed char S[4 * BUFSZ];   // 128 KB

    // XCD swizzle: 256 blocks -> each XCD a 4(bm) x 8(bn) rectangle.
    const int flat = blockIdx.y * gridDim.x + blockIdx.x;
    const int xcd  = flat & 7;
    const int idx  = flat >> 3;                 // 0..31
    const int bm   = ((xcd >> 1) << 2) + (idx & 3);
    const int bn   = ((xcd & 1) << 3) + (idx >> 2);

    const int t = threadIdx.x;
    const int lane = t & 63;
    const int wave = t >> 6;                    // 0..7
    const int wm = (wave >> 2) * 128;           // 2 waves in M
    const int wn = (wave & 3) * 64;             // 4 waves in N
    const int l31 = lane & 31, lh = lane >> 5;

    // --- staging: thread t covers dest chunks cidx = t and t+512 of each tile
    const signed char* ga[2];
    const signed char* gb[2];
    int ldsA[2], ldsB[2];
    #pragma unroll
    for (int h = 0; h < 2; ++h) {
        const int cidx = t + 512 * h;           // 0..1023
        const int row  = cidx >> 2;             // 0..255
        const int g    = (cidx & 3) ^ swzC(row);// pre-swizzled global chunk
        ga[h] = A + (size_t)(bm * BM + row) * DIM + g * 16;
        gb[h] = B + (size_t)(bn * BM + row) * DIM + g * 16;
        ldsA[h] = cidx * 16;                    // linear LDS dest (A region)
        ldsB[h] = ATILE + cidx * 16;            // linear LDS dest (B region)
    }

    // --- loop-invariant read offsets (within one buffer)
    int offA[4][2], offB[2][2];
    #pragma unroll
    for (int i = 0; i < 4; ++i)
        #pragma unroll
        for (int s = 0; s < 2; ++s) {
            const int r = wm + i * 32 + l31;
            offA[i][s] = r * BK + (((2 * s + lh) ^ swzC(r)) * 16);
        }
    #pragma unroll
    for (int j = 0; j < 2; ++j)
        #pragma unroll
        for (int s = 0; s < 2; ++s) {
            const int c = wn + j * 32 + l31;
            offB[j][s] = ATILE + c * BK + (((2 * s + lh) ^ swzC(c)) * 16);
        }

    v16i acc[4][2] = {};

#define STAGE(P) do {                                                          \
        async16(ga[0], &S[(P) * BUFSZ + ldsA[0]]); ga[0] += BK;                \
        async16(ga[1], &S[(P) * BUFSZ + ldsA[1]]); ga[1] += BK;                \
        async16(gb[0], &S[(P) * BUFSZ + ldsB[0]]); gb[0] += BK;                \
        async16(gb[1], &S[(P) * BUFSZ + ldsB[1]]); gb[1] += BK;                \
    } while (0)

#define MFMA8(A0, A1, A2, A3, B0, B1) do {                                     \
        __builtin_amdgcn_s_setprio(1);                                         \
        acc[0][0] = __builtin_amdgcn_mfma_i32_32x32x32_i8(A0, B0, acc[0][0], 0, 0, 0); \
        acc[0][1] = __builtin_amdgcn_mfma_i32_32x32x32_i8(A0, B1, acc[0][1], 0, 0, 0); \
        acc[1][0] = __builtin_amdgcn_mfma_i32_32x32x32_i8(A1, B0, acc[1][0], 0, 0, 0); \
        acc[1][1] = __builtin_amdgcn_mfma_i32_32x32x32_i8(A1, B1, acc[1][1], 0, 0, 0); \
        acc[2][0] = __builtin_amdgcn_mfma_i32_32x32x32_i8(A2, B0, acc[2][0], 0, 0, 0); \
        acc[2][1] = __builtin_amdgcn_mfma_i32_32x32x32_i8(A2, B1, acc[2][1], 0, 0, 0); \
        acc[3][0] = __builtin_amdgcn_mfma_i32_32x32x32_i8(A3, B0, acc[3][0], 0, 0, 0); \
        acc[3][1] = __builtin_amdgcn_mfma_i32_32x32x32_i8(A3, B1, acc[3][1], 0, 0, 0); \
        __builtin_amdgcn_s_setprio(0);                                         \
    } while (0)

    // One K-tile substep, 2-phase.  SP = buffer staged (tile t+3), P = tile t.
#define SUBSTEP(P, SP, VN) do {                                                \
        VMCNT(VN); BARRIER();            /* tile P landed; buf SP free */      \
        STAGE(SP);                       /* 4 gload_lds, stay in flight */     \
        const v4i a0s0 = *(const v4i*)&S[(P) * BUFSZ + offA[0][0]];            \
        const v4i a1s0 = *(const v4i*)&S[(P) * BUFSZ + offA[1][0]];            \
        const v4i a2s0 = *(const v4i*)&S[(P) * BUFSZ + offA[2][0]];            \
        const v4i a3s0 = *(const v4i*)&S[(P) * BUFSZ + offA[3][0]];            \
        const v4i b0s0 = *(const v4i*)&S[(P) * BUFSZ + offB[0][0]];            \
        const v4i b1s0 = *(const v4i*)&S[(P) * BUFSZ + offB[1][0]];            \
        BARRIER();                       /* phase edge */                      \
        MFMA8(a0s0, a1s0, a2s0, a3s0, b0s0, b1s0);                             \
        const v4i a0s1 = *(const v4i*)&S[(P) * BUFSZ + offA[0][1]];            \
        const v4i a1s1 = *(const v4i*)&S[(P) * BUFSZ + offA[1][1]];            \
        const v4i a2s1 = *(const v4i*)&S[(P) * BUFSZ + offA[2][1]];            \
        const v4i a3s1 = *(const v4i*)&S[(P) * BUFSZ + offA[3][1]];            \
        const v4i b0s1 = *(const v4i*)&S[(P) * BUFSZ + offB[0][1]];            \
        const v4i b1s1 = *(const v4i*)&S[(P) * BUFSZ + offB[1][1]];            \
        BARRIER();                       /* phase edge */                      \
        MFMA8(a0s1, a1s1, a2s1, a3s1, b0s1, b1s1);                             \
    } while (0)

    // tail substep: no STAGE
#define SUBSTEP_NS(P, VN) do {                                                 \
        VMCNT(VN); BARRIER();                                                  \
        const v4i a0s0 = *(const v4i*)&S[(P) * BUFSZ + offA[0][0]];            \
        const v4i a1s0 = *(const v4i*)&S[(P) * BUFSZ + offA[1][0]];            \
        const v4i a2s0 = *(const v4i*)&S[(P) * BUFSZ + offA[2][0]];            \
        const v4i a3s0 = *(const v4i*)&S[(P) * BUFSZ + offA[3][0]];            \
        const v4i b0s0 = *(const v4i*)&S[(P) * BUFSZ + offB[0][0]];            \
        const v4i b1s0 = *(const v4i*)&S[(P) * BUFSZ + offB[1][0]];            \
        BARRIER();                                                             \
        MFMA8(a0s0, a1s0, a2s0, a3s0, b0s0, b1s0);                             \
        const v4i a0s1 = *(const v4i*)&S[(P) * BUFSZ + offA[0][1]];            \
        const v4i a1s1 = *(const v4i*)&S[(P) * BUFSZ + offA[1][1]];            \
        const v4i a2s1 = *(const v4i*)&S[(P) * BUFSZ + offA[2][1]];            \
        const v4i a3s1 = *(const v4i*)&S[(P) * BUFSZ + offA[3][1]];            \
        const v4i b0s1 = *(const v4i*)&S[(P) * BUFSZ + offB[0][1]];            \
        const v4i b1s1 = *(const v4i*)&S[(P) * BUFSZ + offB[1][1]];            \
        BARRIER();                                                             \
        MFMA8(a0s1, a1s1, a2s1, a3s1, b0s1, b1s1);                             \
    } while (0)

    // 64 K-tiles, tile t -> buf t&3. Prologue stages tiles 0,1,2 (12 loads).
    STAGE(0); STAGE(1); STAGE(2);
    #pragma unroll 1
    for (int it = 0; it < 15; ++it) {
        SUBSTEP(0, 3, 8);                // compute 4it+0, stage 4it+3
        SUBSTEP(1, 0, 8);                // compute 4it+1, stage 4it+4
        SUBSTEP(2, 1, 8);                // compute 4it+2, stage 4it+5
        SUBSTEP(3, 2, 8);                // compute 4it+3, stage 4it+6
    }
    SUBSTEP(0, 3, 8);                    // compute 60, stage 63
    SUBSTEP_NS(1, 8);                    // compute 61 (62,63 in flight)
    SUBSTEP_NS(2, 4);                    // compute 62 (63 in flight)
    SUBSTEP_NS(3, 0);                    // compute 63

#undef SUBSTEP
#undef SUBSTEP_NS
#undef STAGE
#undef MFMA8

    // epilogue: out[n,o] = acc * sx[n] * ws[o] + bias[o]
    // C/D: col = lane&31, row = (reg&3) + 8*(reg>>2) + 4*(lane>>5)  [m74/m101]
    #pragma unroll
    for (int j = 0; j < 2; ++j) {
        const int col = bn * BM + wn + j * 32 + l31;
        const float ws = wscale[col];
        const float bs = bias[col];
        #pragma unroll
        for (int i = 0; i < 4; ++i) {
            const int rb = bm * BM + wm + i * 32 + 4 * lh;
            #pragma unroll
            for (int r = 0; r < 16; ++r) {
                const int row = rb + (r & 3) + 8 * (r >> 2);
                out[(size_t)row * DIM + col] =
                    ((float)acc[i][j][r] * rowScale[row]) * ws + bs;
            }
        }
    }
}

// ---------------------------------------------------------------------------
extern "C" void kernel_launch(void* const* d_in, const int* in_sizes, int n_in,
                              void* d_out, int out_size, void* d_ws, size_t ws_size,
                              hipStream_t stream) {
    const float* x      = (const float*)d_in[0];
    const int*   wint   = (const int*)d_in[1];
    const float* wscale = (const float*)d_in[2];
    const float* bias   = (const float*)d_in[3];
    float* out = (float*)d_out;

    signed char* q8 = (signed char*)d_ws;                         // 16 MB
    signed char* w8 = q8 + (size_t)DIM * DIM;                     // 16 MB
    float* sx = (float*)(w8 + (size_t)DIM * DIM);                 // 16 KB

    prep<<<4096 + 16384, 256, 0, stream>>>(x, wint, q8, w8, sx);
    gemm_q8<<<dim3(DIM / BM, DIM / BM), 512, 0, stream>>>(q8, w8, sx, wscale, bias, out);
}